// Round 4
// baseline (1834.783 us; speedup 1.0000x reference)
//
#include <hip/hip_runtime.h>

typedef unsigned short ushort_t;
typedef unsigned int uint_t;
typedef __attribute__((ext_vector_type(8))) short short8;
typedef __attribute__((ext_vector_type(4))) float f32x4;
typedef __attribute__((ext_vector_type(4))) uint_t uint4a;
typedef __attribute__((ext_vector_type(2))) uint_t uint2a;

#define Tn 256
#define Bn 64
#define Hn 512
#define En 256
#define G4 2048
#define Nt 6

// bf16 NaN sentinel: f2bf of any finite float can yield at most 0x7F80 (inf);
// 0x7FC0 (quiet NaN) is unreachable => safe "not yet written" marker.
#define SENT 0x7FC07FC0u

// ---------- helpers ----------
__device__ inline ushort_t f2bf(float f) {
    uint_t u = __float_as_uint(f);
    uint_t r = u + 0x7FFFu + ((u >> 16) & 1u);
    return (ushort_t)(r >> 16);
}
__device__ inline float bf2f(ushort_t h) { return __uint_as_float(((uint_t)h) << 16); }
__device__ inline float sigm(float x) { return 1.f / (1.f + __expf(-x)); }
__device__ inline float tanh_(float x) { return 2.f / (1.f + __expf(-2.f * x)) - 1.f; }

// sc1 = device scope: bypass L1+L2, coherence point = Infinity Cache.
// !! inline-asm loads are INVISIBLE to the compiler's waitcnt pass: ALWAYS
// vm_drain() before use, plus sched_barrier(0) when the consumer is
// register-only (sentinel compares) — "memory" clobber does not order those.
__device__ inline uint4a gload16_sc1(const void* p) {
    uint4a r;
    asm volatile("global_load_dwordx4 %0, %1, off sc1" : "=v"(r) : "v"(p) : "memory");
    return r;
}
__device__ inline void gstore4_sc1(void* p, uint_t v) {
    asm volatile("global_store_dword %0, %1, off sc1" :: "v"(p), "v"(v) : "memory");
}
__device__ inline void vm_drain() { asm volatile("s_waitcnt vmcnt(0)" ::: "memory"); }

// ---------- ws layout (bytes) ----------
// hbuf: [dir][257 slots][64 batch][512] bf16. Slot s = h-state after s steps
// (slot 0 = h0). Write-once per launch => data-is-the-flag synchronization.
#define OFF_XBF    0u               // 16384*256 bf16        = 8,388,608
#define OFF_WIH    8388608u         // 2*2048*256 bf16       = 2,097,152
#define OFF_WHH    10485760u        // 2*2048*512 bf16       = 4,194,304
#define OFF_HBUF   14680064u        // 2*257*64*512 bf16     = 33,685,504 (end 48,365,568)
#define OFF_EMIS   8388608u         // overlays WIH (dead after lstm; prep rewrites each call)

#define SLOT_U     32768u           // ushorts per slot (64*512)
#define DIR_U      8421376u         // ushorts per dir (257*32768)

// ---------- kernel 1: prep ----------
__global__ void prep_kernel(const int* __restrict__ sent, const float* __restrict__ embed,
                            const float* __restrict__ Wihf, const float* __restrict__ Whhf,
                            const float* __restrict__ Wihb, const float* __restrict__ Whhb,
                            const float* __restrict__ h0, float* __restrict__ out,
                            ushort_t* __restrict__ x_bf, ushort_t* __restrict__ Wih_bf,
                            ushort_t* __restrict__ Whh_bf, ushort_t* __restrict__ hbuf) {
    long i = (long)blockIdx.x * 256 + threadIdx.x;
    const long nA = 524288, nB = 262144, nC = 1048576, nD = 32768, nE = 1048576;
    if (i < nA) {  // Whh cast: [dir][2048][512], 4 elems
        long e4 = i << 2;
        long d = e4 >> 20, r = e4 & 1048575;
        const float* W = d ? Whhb : Whhf;
        float4 v = *(const float4*)(W + r);
        uint2a pv;
        pv.x = (uint_t)f2bf(v.x) | ((uint_t)f2bf(v.y) << 16);
        pv.y = (uint_t)f2bf(v.z) | ((uint_t)f2bf(v.w) << 16);
        *(uint2a*)(Whh_bf + e4) = pv;
        return;
    }
    i -= nA;
    if (i < nB) {  // Wih cast: [dir][2048][256], 4 elems
        long e4 = i << 2;
        long d = e4 >> 19, r = e4 & 524287;
        const float* W = d ? Wihb : Wihf;
        float4 v = *(const float4*)(W + r);
        uint2a pv;
        pv.x = (uint_t)f2bf(v.x) | ((uint_t)f2bf(v.y) << 16);
        pv.y = (uint_t)f2bf(v.z) | ((uint_t)f2bf(v.w) << 16);
        *(uint2a*)(Wih_bf + (d << 19) + r) = pv;
        return;
    }
    i -= nB;
    if (i < nC) {  // x gather: row = t*B+b, 4 elems within one embed row
        long e4 = i << 2;
        long row = e4 >> 8, e = e4 & 255;
        int tok = sent[row];
        float4 v = *(const float4*)(embed + (size_t)tok * 256 + e);
        uint2a pv;
        pv.x = (uint_t)f2bf(v.x) | ((uint_t)f2bf(v.y) << 16);
        pv.y = (uint_t)f2bf(v.z) | ((uint_t)f2bf(v.w) << 16);
        *(uint2a*)(x_bf + e4) = pv;
        return;
    }
    i -= nC;
    if (i < nD) {  // h0 -> hbuf[dir][slot 0][b][jw*2..+1], one bf16 pair (sc1)
        long dir = i >> 14, rem = i & 16383;
        long b = rem >> 8, jw = rem & 255;
        const float* hp = h0 + (size_t)dir * Bn * Hn + (size_t)b * Hn + jw * 2;
        gstore4_sc1(hbuf + (size_t)dir * DIR_U + b * 512 + jw * 2,
                    (uint_t)f2bf(hp[0]) | ((uint_t)f2bf(hp[1]) << 16));
        return;
    }
    i -= nD;
    if (i < nE) {  // sentinel fill: slots 1..256 both dirs, 32B/thread.
        long dir = i >> 19, rem = i & 524287;
        ushort_t* p = hbuf + (size_t)dir * DIR_U + SLOT_U + (size_t)rem * 16;
        uint4a s; s.x = SENT; s.y = SENT; s.z = SENT; s.w = SENT;
        *(uint4a*)p = s;
        *(uint4a*)(p + 8) = s;
        return;
    }
    if (i == nE) { out[0] = 0.f; }
}

// ---------- kernel 2: persistent fused BiLSTM, 2 streams per WG ----------
// 64 WGs: dir(2) x gate-slice(32). 256 threads. Each WG serves BOTH
// batch-half streams P(bh=0), Q(bh=1) of its dir — same gate rows, so the
// W_ih/W_hh register fragments are shared. The two streams are independent
// recurrences: P's h-load flies during Q's compute block and vice versa
// (latency hiding). Data-is-the-flag (sentinel) protocol per stream,
// bounded retry => no deadlock, wrong-answer-not-hang on protocol bug.
__global__ void __launch_bounds__(256, 1) lstm_kernel(
    const ushort_t* __restrict__ x_bf, const ushort_t* __restrict__ Wih_bf,
    const ushort_t* __restrict__ Whh_bf, const float* __restrict__ biasf,
    const float* __restrict__ biasb, const float* __restrict__ c0,
    const int* __restrict__ mask, ushort_t* __restrict__ hbuf) {

    __shared__ __align__(16) ushort_t x_s[2][32 * 264];    // [stream], single-buffered
    __shared__ __align__(16) ushort_t h_s[2][32 * 520];    // [stream]
    __shared__ __align__(16) float gates_s[2][64 * 35];    // [stream]

    const int tid = threadIdx.x;
    const int wid = blockIdx.x;
    const int dir = wid >> 5;
    const int gs  = wid & 31;
    const int j0  = gs * 16;

    const int lane = tid & 63;
    const int wv = tid >> 6;            // wave = gate type (i,f,g,o)
    const int qo = (lane >> 4) * 8;     // k-chunk offset in fragment
    const int ml = lane & 15;

    // persistent B fragments (W_ih: 8 ksteps, W_hh: 16 ksteps), SHARED by
    // both streams (same dir, same gate rows) — 96 VGPRs total.
    const int grow = wv * 512 + j0 + ml;   // global gate row 0..2047
    short8 bxf[8], bhf[16];
    {
        const ushort_t* wr = Wih_bf + (size_t)dir * G4 * En + (size_t)grow * En + qo;
        #pragma unroll
        for (int ks = 0; ks < 8; ++ks) bxf[ks] = *(const short8*)(wr + ks * 32);
        const ushort_t* wr2 = Whh_bf + (size_t)dir * G4 * Hn + (size_t)grow * Hn + qo;
        #pragma unroll
        for (int ks = 0; ks < 16; ++ks) bhf[ks] = *(const short8*)(wr2 + ks * 32);
    }
    const float bv = (dir ? biasb : biasf)[grow];

    // update-phase mapping: thread -> (2 consecutive j, one batch-in-pane)
    const int jp = (tid & 7) * 2;
    const int bl = tid >> 3;            // batch within 32-pane
    float creg[2][2];
    #pragma unroll
    for (int S = 0; S < 2; ++S)
        #pragma unroll
        for (int r = 0; r < 2; ++r)
            creg[S][r] = c0[(size_t)dir * Bn * Hn + (size_t)(S * 32 + bl) * Hn + j0 + jp + r];

    const ushort_t* xbaseS[2] = { x_bf, x_bf + (size_t)32 * En };
    ushort_t* hpane[2] = { hbuf + (size_t)dir * DIR_U,
                           hbuf + (size_t)dir * DIR_U + (size_t)32 * 512 };

    uint4 xreg[4];
    uint4a hreg[8];

    // prologue: stage x[t0] for both streams; issue P.h(0) loads
    {
        const int t0 = dir ? (Tn - 1) : 0;
        #pragma unroll
        for (int S = 0; S < 2; ++S) {
            const uint4* g4 = (const uint4*)(xbaseS[S] + (size_t)t0 * Bn * En);
            #pragma unroll
            for (int k = 0; k < 4; ++k) xreg[k] = g4[tid + k * 256];
            #pragma unroll
            for (int k = 0; k < 4; ++k) {
                int c16 = tid + k * 256;
                *(uint4*)&x_s[S][(c16 >> 5) * 264 + (c16 & 31) * 8] = xreg[k];
            }
        }
        #pragma unroll
        for (int k = 0; k < 8; ++k)
            hreg[k] = gload16_sc1(hpane[0] + (size_t)(tid + k * 256) * 8);
    }
    __syncthreads();

// One stream block: validate+stage h(s) -> x-MFMAs -> [issue partner h-load]
// -> x[t+1] prefetch -> h-MFMAs -> gates -> barrier -> x_s write -> update
// -> h(s+1) store -> barrier.  ISSUE_STMT flies through ~1.5 compute blocks.
#define STREAM_BLOCK(S, BOFF, ISSUE_STMT)                                      \
    {                                                                          \
        vm_drain();                                                            \
        __builtin_amdgcn_sched_barrier(0);                                     \
        {                                                                      \
            const ushort_t* hp0 = hpane[S] + (size_t)s * SLOT_U;               \
            bool ok = true;                                                    \
            _Pragma("unroll")                                                  \
            for (int k = 0; k < 8; ++k)                                        \
                _Pragma("unroll")                                              \
                for (int w = 0; w < 4; ++w) ok &= (hreg[k][w] != SENT);        \
            int guard = 65536;                                                 \
            while (!ok && --guard) {                                           \
                __builtin_amdgcn_s_sleep(1);                                   \
                _Pragma("unroll")                                              \
                for (int k = 0; k < 8; ++k)                                    \
                    hreg[k] = gload16_sc1(hp0 + (size_t)(tid + k * 256) * 8);  \
                vm_drain();                                                    \
                __builtin_amdgcn_sched_barrier(0);                             \
                ok = true;                                                     \
                _Pragma("unroll")                                              \
                for (int k = 0; k < 8; ++k)                                    \
                    _Pragma("unroll")                                          \
                    for (int w = 0; w < 4; ++w) ok &= (hreg[k][w] != SENT);    \
            }                                                                  \
        }                                                                      \
        _Pragma("unroll")                                                      \
        for (int k = 0; k < 8; ++k) {                                          \
            int c16 = tid + k * 256;                                           \
            *(uint4a*)&h_s[S][(c16 >> 6) * 520 + (c16 & 63) * 8] = hreg[k];    \
        }                                                                      \
        __syncthreads();                                                       \
        const int mv = mask[t * Bn + (BOFF) + bl];                             \
        f32x4 acc0, acc1;                                                      \
        _Pragma("unroll")                                                      \
        for (int r = 0; r < 4; ++r) { acc0[r] = bv; acc1[r] = bv; }            \
        const ushort_t* xr0 = &x_s[S][ml * 264 + qo];                          \
        const ushort_t* xr1 = &x_s[S][(16 + ml) * 264 + qo];                   \
        _Pragma("unroll")                                                      \
        for (int ks = 0; ks < 8; ++ks) {                                       \
            short8 a0 = *(const short8*)(xr0 + ks * 32);                       \
            short8 a1 = *(const short8*)(xr1 + ks * 32);                       \
            acc0 = __builtin_amdgcn_mfma_f32_16x16x32_bf16(a0, bxf[ks], acc0, 0, 0, 0); \
            acc1 = __builtin_amdgcn_mfma_f32_16x16x32_bf16(a1, bxf[ks], acc1, 0, 0, 0); \
        }                                                                      \
        ISSUE_STMT;                                                            \
        if (s < Tn - 1) {                                                      \
            const int tn = dir ? (Tn - 2 - s) : (s + 1);                       \
            const uint4* g4 = (const uint4*)(xbaseS[S] + (size_t)tn * Bn * En);\
            _Pragma("unroll")                                                  \
            for (int k = 0; k < 4; ++k) xreg[k] = g4[tid + k * 256];           \
        }                                                                      \
        {                                                                      \
            const ushort_t* hr0 = &h_s[S][ml * 520 + qo];                      \
            const ushort_t* hr1 = &h_s[S][(16 + ml) * 520 + qo];               \
            _Pragma("unroll")                                                  \
            for (int ks = 0; ks < 16; ++ks) {                                  \
                short8 a0 = *(const short8*)(hr0 + ks * 32);                   \
                short8 a1 = *(const short8*)(hr1 + ks * 32);                   \
                acc0 = __builtin_amdgcn_mfma_f32_16x16x32_bf16(a0, bhf[ks], acc0, 0, 0, 0); \
                acc1 = __builtin_amdgcn_mfma_f32_16x16x32_bf16(a1, bhf[ks], acc1, 0, 0, 0); \
            }                                                                  \
            int nl = wv * 16 + ml;                                             \
            int br = (lane >> 4) * 4;                                          \
            _Pragma("unroll")                                                  \
            for (int r = 0; r < 4; ++r) {                                      \
                gates_s[S][nl * 35 + br + r]      = acc0[r];                   \
                gates_s[S][nl * 35 + 16 + br + r] = acc1[r];                   \
            }                                                                  \
        }                                                                      \
        __syncthreads();                                                       \
        if (s < Tn - 1) {                                                      \
            _Pragma("unroll")                                                  \
            for (int k = 0; k < 4; ++k) {                                      \
                int c16 = tid + k * 256;                                       \
                *(uint4*)&x_s[S][(c16 >> 5) * 264 + (c16 & 31) * 8] = xreg[k]; \
            }                                                                  \
        }                                                                      \
        {                                                                      \
            ushort_t hu[2];                                                    \
            _Pragma("unroll")                                                  \
            for (int r = 0; r < 2; ++r) {                                      \
                int j = jp + r;                                                \
                float iv  = gates_s[S][j * 35 + bl];                           \
                float fvv = gates_s[S][(16 + j) * 35 + bl];                    \
                float gv  = gates_s[S][(32 + j) * 35 + bl];                    \
                float ov  = gates_s[S][(48 + j) * 35 + bl];                    \
                float cn = sigm(fvv) * creg[S][r] + sigm(iv) * tanh_(gv);      \
                float hn = sigm(ov) * tanh_(cn);                               \
                float hp = bf2f(h_s[S][bl * 520 + j0 + j]);                    \
                float h2;                                                      \
                if (mv) { creg[S][r] = cn; h2 = hn; }                          \
                else    { h2 = hp; }                                           \
                hu[r] = f2bf(h2);                                              \
            }                                                                  \
            gstore4_sc1(hpane[S] + (size_t)(s + 1) * SLOT_U + (size_t)bl * 512 + j0 + jp, \
                        (uint_t)hu[0] | ((uint_t)hu[1] << 16));                \
        }                                                                      \
        __syncthreads();                                                       \
    }

    for (int s = 0; s < Tn; ++s) {
        const int t = dir ? (Tn - 1 - s) : s;

        // P block; mid-compute, issue Q.h(s) (stored end of prev iter: ample V)
        STREAM_BLOCK(0, 0,
            {
                const ushort_t* qp = hpane[1] + (size_t)s * SLOT_U;
                _Pragma("unroll")
                for (int k = 0; k < 8; ++k)
                    hreg[k] = gload16_sc1(qp + (size_t)(tid + k * 256) * 8);
            });

        // Q block; mid-compute, issue P.h(s+1) (stored one barrier ago;
        // flight = rest of Q block => visible by next-iter validate)
        STREAM_BLOCK(1, 32,
            {
                if (s + 1 < Tn) {
                    const ushort_t* pp = hpane[0] + (size_t)(s + 1) * SLOT_U;
                    _Pragma("unroll")
                    for (int k = 0; k < 8; ++k)
                        hreg[k] = gload16_sc1(pp + (size_t)(tid + k * 256) * 8);
                }
            });
    }
#undef STREAM_BLOCK
}

// ---------- kernel 3: emission projection (wave per row) ----------
// h_masked[t] = mask(t) ? hbuf[dir0][t+1] / hbuf[dir1][256-t] : 0.
__global__ void emis_kernel(const ushort_t* __restrict__ hbuf, const int* __restrict__ mask,
                            const float* __restrict__ Wout, const float* __restrict__ bout,
                            float* __restrict__ emis) {
    int row = blockIdx.x * 4 + (threadIdx.x >> 6);   // t*64 + b
    int lane = threadIdx.x & 63;
    int t = row >> 6, b = row & 63;
    float mf = mask[row] ? 1.f : 0.f;
    size_t slot = (lane < 32) ? (size_t)(t + 1) * SLOT_U
                              : (size_t)DIR_U + (size_t)(Tn - t) * SLOT_U;
    const ushort_t* hr = hbuf + slot + (size_t)b * 512 + (lane & 31) * 16;
    short8 h0v = *(const short8*)(hr);
    short8 h1v = *(const short8*)(hr + 8);
    float hv[16];
    #pragma unroll
    for (int j = 0; j < 8; ++j) {
        hv[j]     = bf2f((ushort_t)h0v[j]);
        hv[j + 8] = bf2f((ushort_t)h1v[j]);
    }
    float acc[6];
    #pragma unroll
    for (int n = 0; n < Nt; ++n) {
        const float* w = Wout + n * 1024 + lane * 16;   // lane*16 == concat index
        float a = 0.f;
        #pragma unroll
        for (int j = 0; j < 16; ++j) a += hv[j] * w[j];
        acc[n] = a;
    }
    #pragma unroll
    for (int n = 0; n < Nt; ++n) {
        float v = acc[n];
        #pragma unroll
        for (int off = 32; off; off >>= 1) v += __shfl_down(v, off);
        if (lane == 0) emis[row * Nt + n] = v * mf + bout[n];
    }
}

// ---------- kernel 4: CRF LLH (one wave per batch) ----------
__global__ void crf_kernel(const int* __restrict__ tags, const int* __restrict__ mask,
                           const float* __restrict__ emis, const float* __restrict__ trans,
                           const float* __restrict__ startt, const float* __restrict__ endt,
                           float* __restrict__ out) {
    int b = blockIdx.x;
    int lane = threadIdx.x;

    float part = 0.f;
    int mc = 0;
    for (int t = lane; t < Tn; t += 64) {
        int mv = mask[t * Bn + b];
        mc += mv;
        if (t >= 1) {
            int tp = tags[(t - 1) * Bn + b], tc = tags[t * Bn + b];
            part += (trans[tp * Nt + tc] + emis[(t * Bn + b) * Nt + tc]) * (float)mv;
        }
    }
    #pragma unroll
    for (int off = 32; off; off >>= 1) {
        part += __shfl_down(part, off);
        mc += __shfl_down(mc, off);
    }
    float num = 0.f;
    if (lane == 0) {
        int t0g = tags[b];
        num = startt[t0g] + emis[b * Nt + t0g] + part;
        int last = mc - 1;
        num += endt[tags[last * Bn + b]];
    }

    if (lane < Nt) {
        int j = lane;
        float tr[6];
        #pragma unroll
        for (int i = 0; i < Nt; ++i) tr[i] = trans[i * Nt + j];
        float score = startt[j] + emis[b * Nt + j];
        float e_nx = emis[(Bn + b) * Nt + j];
        int   m_nx = mask[Bn + b];
        for (int t = 1; t < Tn; ++t) {
            float e = e_nx;
            int mv = m_nx;
            if (t + 1 < Tn) {
                e_nx = emis[((t + 1) * Bn + b) * Nt + j];
                m_nx = mask[(t + 1) * Bn + b];
            }
            float v[6];
            float mx = -1e30f;
            #pragma unroll
            for (int i = 0; i < Nt; ++i) { v[i] = __shfl(score, i) + tr[i]; mx = fmaxf(mx, v[i]); }
            float sm = 0.f;
            #pragma unroll
            for (int i = 0; i < Nt; ++i) sm += __expf(v[i] - mx);
            float nxtv = mx + __logf(sm) + e;
            score = mv > 0 ? nxtv : score;
        }
        float fvv = score + endt[j];
        float m2 = fvv;
        #pragma unroll
        for (int i = 0; i < Nt; ++i) m2 = fmaxf(m2, __shfl(fvv, i));
        float s2 = 0.f;
        #pragma unroll
        for (int i = 0; i < Nt; ++i) s2 += __expf(__shfl(fvv, i) - m2);
        if (lane == 0) {
            float denom = m2 + __logf(s2);
            atomicAdd(out, num - denom);
        }
    }
}

extern "C" void kernel_launch(void* const* d_in, const int* in_sizes, int n_in,
                              void* d_out, int out_size, void* d_ws, size_t ws_size,
                              hipStream_t stream) {
    (void)in_sizes; (void)n_in; (void)out_size; (void)ws_size;
    const int*   sent  = (const int*)d_in[0];
    const int*   tags  = (const int*)d_in[1];
    const int*   mask  = (const int*)d_in[2];
    const float* h0    = (const float*)d_in[3];
    const float* c0    = (const float*)d_in[4];
    const float* embed = (const float*)d_in[5];
    const float* Wihf  = (const float*)d_in[6];
    const float* Whhf  = (const float*)d_in[7];
    const float* bf_   = (const float*)d_in[8];
    const float* Wihb  = (const float*)d_in[9];
    const float* Whhb  = (const float*)d_in[10];
    const float* bb_   = (const float*)d_in[11];
    const float* Wout  = (const float*)d_in[12];
    const float* bout  = (const float*)d_in[13];
    const float* trans = (const float*)d_in[14];
    const float* stt   = (const float*)d_in[15];
    const float* ent   = (const float*)d_in[16];
    float* out = (float*)d_out;
    char* ws = (char*)d_ws;

    ushort_t* x_bf   = (ushort_t*)(ws + OFF_XBF);
    ushort_t* Wih_bf = (ushort_t*)(ws + OFF_WIH);
    ushort_t* Whh_bf = (ushort_t*)(ws + OFF_WHH);
    ushort_t* hbuf   = (ushort_t*)(ws + OFF_HBUF);
    float*    emis   = (float*)(ws + OFF_EMIS);

    // prep threads: 524288+262144+1048576+32768+1048576+1 = 2,916,353
    prep_kernel<<<11393, 256, 0, stream>>>(sent, embed, Wihf, Whhf, Wihb, Whhb,
                                           h0, out, x_bf, Wih_bf, Whh_bf, hbuf);
    lstm_kernel<<<64, 256, 0, stream>>>(x_bf, Wih_bf, Whh_bf, bf_, bb_, c0,
                                        mask, hbuf);
    emis_kernel<<<4096, 256, 0, stream>>>(hbuf, mask, Wout, bout, emis);
    crf_kernel<<<64, 64, 0, stream>>>(tags, mask, emis, trans, stt, ent, out);
}

// Round 5
// 1096.391 us; speedup vs baseline: 1.6735x; 1.6735x over previous
//
#include <hip/hip_runtime.h>

typedef unsigned short ushort_t;
typedef unsigned int uint_t;
typedef __attribute__((ext_vector_type(8))) short short8;
typedef __attribute__((ext_vector_type(4))) float f32x4;
typedef __attribute__((ext_vector_type(4))) uint_t uint4a;
typedef __attribute__((ext_vector_type(2))) uint_t uint2a;

#define Tn 256
#define Bn 64
#define Hn 512
#define En 256
#define G4 2048
#define Nt 6

// bf16 NaN sentinel: f2bf of any finite float can yield at most 0x7F80 (inf);
// 0x7FC0 (quiet NaN) is unreachable => safe "not yet written" marker.
#define SENT 0x7FC07FC0u

// ---------- helpers ----------
__device__ inline ushort_t f2bf(float f) {
    uint_t u = __float_as_uint(f);
    uint_t r = u + 0x7FFFu + ((u >> 16) & 1u);
    return (ushort_t)(r >> 16);
}
__device__ inline float bf2f(ushort_t h) { return __uint_as_float(((uint_t)h) << 16); }
__device__ inline float sigm(float x) { return 1.f / (1.f + __expf(-x)); }
__device__ inline float tanh_(float x) { return 2.f / (1.f + __expf(-2.f * x)) - 1.f; }

// All steady-loop VMEM is inline asm so the wave's vmcnt ledger is fully
// ours (the compiler otherwise inserts its own vmcnt(0) before LDS writes
// of prefetched data, draining our invisible sc1 ops with zero slack).
// sc1 = device scope (IF$ coherence point); plain = L2-cached (x, mask).
// !! asm loads are invisible to the compiler's waitcnt pass: vm_drain()
// before use + sched_barrier(0) so register-only consumers aren't hoisted.
__device__ inline uint4a gload16_sc1(const void* p) {
    uint4a r;
    asm volatile("global_load_dwordx4 %0, %1, off sc1" : "=v"(r) : "v"(p) : "memory");
    return r;
}
__device__ inline uint4a gload16_pl(const void* p) {
    uint4a r;
    asm volatile("global_load_dwordx4 %0, %1, off" : "=v"(r) : "v"(p) : "memory");
    return r;
}
__device__ inline int gload4_pl(const void* p) {
    int r;
    asm volatile("global_load_dword %0, %1, off" : "=v"(r) : "v"(p) : "memory");
    return r;
}
__device__ inline void gstore4_sc1(void* p, uint_t v) {
    asm volatile("global_store_dword %0, %1, off sc1" :: "v"(p), "v"(v) : "memory");
}
__device__ inline void vm_drain() { asm volatile("s_waitcnt vmcnt(0)" ::: "memory"); }

// ---------- ws layout (bytes) ----------
// hbuf: [dir][257 slots][64 batch][512] bf16. Slot s = h-state after s steps
// (slot 0 = h0). Write-once per launch => data-is-the-flag synchronization.
#define OFF_XBF    0u               // 16384*256 bf16        = 8,388,608
#define OFF_WIH    8388608u         // 2*2048*256 bf16       = 2,097,152
#define OFF_WHH    10485760u        // 2*2048*512 bf16       = 4,194,304
#define OFF_HBUF   14680064u        // 2*257*64*512 bf16     = 33,685,504 (end 48,365,568)
#define OFF_EMIS   8388608u         // overlays WIH (dead after lstm; prep rewrites each call)

#define SLOT_U     32768u           // ushorts per slot (64*512)
#define DIR_U      8421376u         // ushorts per dir (257*32768)

// ---------- kernel 1: prep ----------
__global__ void prep_kernel(const int* __restrict__ sent, const float* __restrict__ embed,
                            const float* __restrict__ Wihf, const float* __restrict__ Whhf,
                            const float* __restrict__ Wihb, const float* __restrict__ Whhb,
                            const float* __restrict__ h0, float* __restrict__ out,
                            ushort_t* __restrict__ x_bf, ushort_t* __restrict__ Wih_bf,
                            ushort_t* __restrict__ Whh_bf, ushort_t* __restrict__ hbuf) {
    long i = (long)blockIdx.x * 256 + threadIdx.x;
    const long nA = 524288, nB = 262144, nC = 1048576, nD = 32768, nE = 1048576;
    if (i < nA) {  // Whh cast: [dir][2048][512], 4 elems
        long e4 = i << 2;
        long d = e4 >> 20, r = e4 & 1048575;
        const float* W = d ? Whhb : Whhf;
        float4 v = *(const float4*)(W + r);
        uint2a pv;
        pv.x = (uint_t)f2bf(v.x) | ((uint_t)f2bf(v.y) << 16);
        pv.y = (uint_t)f2bf(v.z) | ((uint_t)f2bf(v.w) << 16);
        *(uint2a*)(Whh_bf + e4) = pv;
        return;
    }
    i -= nA;
    if (i < nB) {  // Wih cast: [dir][2048][256], 4 elems
        long e4 = i << 2;
        long d = e4 >> 19, r = e4 & 524287;
        const float* W = d ? Wihb : Wihf;
        float4 v = *(const float4*)(W + r);
        uint2a pv;
        pv.x = (uint_t)f2bf(v.x) | ((uint_t)f2bf(v.y) << 16);
        pv.y = (uint_t)f2bf(v.z) | ((uint_t)f2bf(v.w) << 16);
        *(uint2a*)(Wih_bf + (d << 19) + r) = pv;
        return;
    }
    i -= nB;
    if (i < nC) {  // x gather: row = t*B+b, 4 elems within one embed row
        long e4 = i << 2;
        long row = e4 >> 8, e = e4 & 255;
        int tok = sent[row];
        float4 v = *(const float4*)(embed + (size_t)tok * 256 + e);
        uint2a pv;
        pv.x = (uint_t)f2bf(v.x) | ((uint_t)f2bf(v.y) << 16);
        pv.y = (uint_t)f2bf(v.z) | ((uint_t)f2bf(v.w) << 16);
        *(uint2a*)(x_bf + e4) = pv;
        return;
    }
    i -= nC;
    if (i < nD) {  // h0 -> hbuf[dir][slot 0][b][jw*2..+1], one bf16 pair (sc1)
        long dir = i >> 14, rem = i & 16383;
        long b = rem >> 8, jw = rem & 255;
        const float* hp = h0 + (size_t)dir * Bn * Hn + (size_t)b * Hn + jw * 2;
        gstore4_sc1(hbuf + (size_t)dir * DIR_U + b * 512 + jw * 2,
                    (uint_t)f2bf(hp[0]) | ((uint_t)f2bf(hp[1]) << 16));
        return;
    }
    i -= nD;
    if (i < nE) {  // sentinel fill: slots 1..256 both dirs, 32B/thread.
        long dir = i >> 19, rem = i & 524287;
        ushort_t* p = hbuf + (size_t)dir * DIR_U + SLOT_U + (size_t)rem * 16;
        uint4a s; s.x = SENT; s.y = SENT; s.z = SENT; s.w = SENT;
        *(uint4a*)p = s;
        *(uint4a*)(p + 8) = s;
        return;
    }
    if (i == nE) { out[0] = 0.f; }
}

// ---------- kernel 2: persistent fused BiLSTM ----------
// 128 WGs: dir(2) x batch-half(2) x gate-slice(32). 256 threads.
// Data-is-the-flag sentinel protocol (R3-verified). New vs R3: the whole
// steady loop's VMEM is inline asm with ONE vm_drain per iteration:
//  A: issue [x4(t+1) plain, mask(t+1) plain, h8(slot s) sc1]
//  B: x-MFMAs (load flight)
//  C: vm_drain (prev h-store is OLDEST here — acked in parallel with the
//     loads, never separately exposed) -> validate/retry -> stage h_s,x_s
//  D: h-MFMAs + gates    E: update + single sc1 h-store (slot s+1)
// No compiler VMEM in the loop => no hidden vmcnt(0) drains.
__global__ void __launch_bounds__(256, 1) lstm_kernel(
    const ushort_t* __restrict__ x_bf, const ushort_t* __restrict__ Wih_bf,
    const ushort_t* __restrict__ Whh_bf, const float* __restrict__ biasf,
    const float* __restrict__ biasb, const float* __restrict__ c0,
    const int* __restrict__ mask, ushort_t* __restrict__ hbuf) {

    __shared__ __align__(16) ushort_t x_s[2][32 * 264];
    __shared__ __align__(16) ushort_t h_s[32 * 520];
    __shared__ __align__(16) float gates_s[64 * 35];

    const int tid = threadIdx.x;
    const int wid = blockIdx.x;
    const int dir = wid >> 6;
    const int bh  = (wid >> 5) & 1;
    const int gs  = wid & 31;
    const int j0  = gs * 16;

    const int lane = tid & 63;
    const int wv = tid >> 6;            // wave = gate type (i,f,g,o)
    const int qo = (lane >> 4) * 8;     // k-chunk offset in fragment
    const int ml = lane & 15;

    // persistent B fragments (W_ih: 8 ksteps, W_hh: 16 ksteps) in VGPRs
    const int grow = wv * 512 + j0 + ml;   // global gate row 0..2047
    short8 bxf[8], bhf[16];
    {
        const ushort_t* wr = Wih_bf + (size_t)dir * G4 * En + (size_t)grow * En + qo;
        #pragma unroll
        for (int ks = 0; ks < 8; ++ks) bxf[ks] = *(const short8*)(wr + ks * 32);
        const ushort_t* wr2 = Whh_bf + (size_t)dir * G4 * Hn + (size_t)grow * Hn + qo;
        #pragma unroll
        for (int ks = 0; ks < 16; ++ks) bhf[ks] = *(const short8*)(wr2 + ks * 32);
    }
    const float bv = (dir ? biasb : biasf)[grow];

    // update-phase mapping: thread -> (2 consecutive j, one batch) => one 4B store
    const int jp = (tid & 7) * 2;
    const int bl = tid >> 3;
    const int bg = bh * 32 + bl;
    float creg[2];
    #pragma unroll
    for (int r = 0; r < 2; ++r)
        creg[r] = c0[(size_t)dir * Bn * Hn + (size_t)bg * Hn + j0 + jp + r];

    const ushort_t* xbase = x_bf + (size_t)bh * 32 * En;
    const ushort_t* hrd = hbuf + (size_t)dir * DIR_U + (size_t)bh * 32 * 512;
    ushort_t*       hwr = hbuf + (size_t)dir * DIR_U + (size_t)bh * 32 * 512;

    // prologue (plain compiler loads, all drained before the asm loop):
    // x[t0] -> x_s[0]; mv(t0)
    {
        const int t0 = dir ? (Tn - 1) : 0;
        const uint4* g4 = (const uint4*)(xbase + (size_t)t0 * Bn * En);
        uint4 xp[4];
        #pragma unroll
        for (int k = 0; k < 4; ++k) xp[k] = g4[tid + k * 256];
        #pragma unroll
        for (int k = 0; k < 4; ++k) {
            int c16 = tid + k * 256;
            *(uint4*)&x_s[0][(c16 >> 5) * 264 + (c16 & 31) * 8] = xp[k];
        }
    }
    int mv = mask[(dir ? (Tn - 1) : 0) * Bn + bg];
    __syncthreads();

    for (int s = 0; s < Tn; ++s) {
        const int t = dir ? (Tn - 1 - s) : s;
        const int cur = s & 1, nxt = cur ^ 1;

        // A: asm bundle — x(t for iter s+1), mask(same), h(slot s).
        //    Issued after prev E barrier => all 4 waves' stores precede.
        const int sn = (s + 1 < Tn) ? s + 1 : Tn - 1;
        const int tn = dir ? (Tn - 1 - sn) : sn;
        uint4a xreg[4];
        {
            const ushort_t* g = xbase + (size_t)tn * Bn * En;
            #pragma unroll
            for (int k = 0; k < 4; ++k)
                xreg[k] = gload16_pl(g + (size_t)(tid + k * 256) * 8);
        }
        int mnx = gload4_pl(&mask[tn * Bn + bg]);
        const ushort_t* hp0 = hrd + (size_t)s * SLOT_U;
        uint4a hreg[8];
        #pragma unroll
        for (int k = 0; k < 8; ++k)
            hreg[k] = gload16_sc1(hp0 + (size_t)(tid + k * 256) * 8);

        // B: all 8 x-part MFMA ksteps (load flight)
        f32x4 acc0, acc1;
        #pragma unroll
        for (int r = 0; r < 4; ++r) { acc0[r] = bv; acc1[r] = bv; }
        const ushort_t* xr0 = &x_s[cur][ml * 264 + qo];
        const ushort_t* xr1 = &x_s[cur][(16 + ml) * 264 + qo];
        #pragma unroll
        for (int ks = 0; ks < 8; ++ks) {
            short8 a0 = *(const short8*)(xr0 + ks * 32);
            short8 a1 = *(const short8*)(xr1 + ks * 32);
            acc0 = __builtin_amdgcn_mfma_f32_16x16x32_bf16(a0, bxf[ks], acc0, 0, 0, 0);
            acc1 = __builtin_amdgcn_mfma_f32_16x16x32_bf16(a1, bxf[ks], acc1, 0, 0, 0);
        }

        // C: the ONE drain. Prev store is oldest (E-tail+barrier+A+B slack,
        //    then overlaps the loads). Validate sentinels; bounded retry.
        vm_drain();
        __builtin_amdgcn_sched_barrier(0);
        {
            bool ok = true;
            #pragma unroll
            for (int k = 0; k < 8; ++k)
                #pragma unroll
                for (int w = 0; w < 4; ++w) ok &= (hreg[k][w] != SENT);
            int guard = 65536;
            while (!ok && --guard) {
                __builtin_amdgcn_s_sleep(2);
                #pragma unroll
                for (int k = 0; k < 8; ++k)
                    hreg[k] = gload16_sc1(hp0 + (size_t)(tid + k * 256) * 8);
                vm_drain();
                __builtin_amdgcn_sched_barrier(0);
                ok = true;
                #pragma unroll
                for (int k = 0; k < 8; ++k)
                    #pragma unroll
                    for (int w = 0; w < 4; ++w) ok &= (hreg[k][w] != SENT);
            }
        }
        #pragma unroll
        for (int k = 0; k < 8; ++k) {
            int c16 = tid + k * 256;
            *(uint4a*)&h_s[(c16 >> 6) * 520 + (c16 & 63) * 8] = hreg[k];
        }
        #pragma unroll
        for (int k = 0; k < 4; ++k) {
            int c16 = tid + k * 256;
            *(uint4a*)&x_s[nxt][(c16 >> 5) * 264 + (c16 & 31) * 8] = xreg[k];
        }
        __syncthreads();

        // D: h-part MFMAs; gates to LDS (stride 35: <=2-way bank aliasing)
        {
            const ushort_t* hr0 = &h_s[ml * 520 + qo];
            const ushort_t* hr1 = &h_s[(16 + ml) * 520 + qo];
            #pragma unroll
            for (int ks = 0; ks < 16; ++ks) {
                short8 a0 = *(const short8*)(hr0 + ks * 32);
                short8 a1 = *(const short8*)(hr1 + ks * 32);
                acc0 = __builtin_amdgcn_mfma_f32_16x16x32_bf16(a0, bhf[ks], acc0, 0, 0, 0);
                acc1 = __builtin_amdgcn_mfma_f32_16x16x32_bf16(a1, bhf[ks], acc1, 0, 0, 0);
            }
            int nl = wv * 16 + ml;
            int br = (lane >> 4) * 4;
            #pragma unroll
            for (int r = 0; r < 4; ++r) {
                gates_s[nl * 35 + br + r]      = acc0[r];
                gates_s[nl * 35 + 16 + br + r] = acc1[r];
            }
        }
        __syncthreads();

        // E: cell update; single sc1 h-store to slot s+1 (fire-and-forget)
        {
            ushort_t hu[2];
            #pragma unroll
            for (int r = 0; r < 2; ++r) {
                int j = jp + r;
                float iv  = gates_s[j * 35 + bl];
                float fvv = gates_s[(16 + j) * 35 + bl];
                float gv  = gates_s[(32 + j) * 35 + bl];
                float ov  = gates_s[(48 + j) * 35 + bl];
                float cn = sigm(fvv) * creg[r] + sigm(iv) * tanh_(gv);
                float hn = sigm(ov) * tanh_(cn);
                float hp = bf2f(h_s[bl * 520 + j0 + j]);
                float h2;
                if (mv) { creg[r] = cn; h2 = hn; }
                else    { h2 = hp; }
                hu[r] = f2bf(h2);
            }
            gstore4_sc1(hwr + (size_t)(s + 1) * SLOT_U + (size_t)bl * 512 + j0 + jp,
                        (uint_t)hu[0] | ((uint_t)hu[1] << 16));
        }
        mv = mnx;
        // protect h_s (read in E) / x_s[nxt] / gates_s for next iteration
        __syncthreads();
    }
}

// ---------- kernel 3: emission projection (wave per row) ----------
// h_masked[t] = mask(t) ? hbuf[dir0][t+1] / hbuf[dir1][256-t] : 0.
__global__ void emis_kernel(const ushort_t* __restrict__ hbuf, const int* __restrict__ mask,
                            const float* __restrict__ Wout, const float* __restrict__ bout,
                            float* __restrict__ emis) {
    int row = blockIdx.x * 4 + (threadIdx.x >> 6);   // t*64 + b
    int lane = threadIdx.x & 63;
    int t = row >> 6, b = row & 63;
    float mf = mask[row] ? 1.f : 0.f;
    size_t slot = (lane < 32) ? (size_t)(t + 1) * SLOT_U
                              : (size_t)DIR_U + (size_t)(Tn - t) * SLOT_U;
    const ushort_t* hr = hbuf + slot + (size_t)b * 512 + (lane & 31) * 16;
    short8 h0v = *(const short8*)(hr);
    short8 h1v = *(const short8*)(hr + 8);
    float hv[16];
    #pragma unroll
    for (int j = 0; j < 8; ++j) {
        hv[j]     = bf2f((ushort_t)h0v[j]);
        hv[j + 8] = bf2f((ushort_t)h1v[j]);
    }
    float acc[6];
    #pragma unroll
    for (int n = 0; n < Nt; ++n) {
        const float* w = Wout + n * 1024 + lane * 16;   // lane*16 == concat index
        float a = 0.f;
        #pragma unroll
        for (int j = 0; j < 16; ++j) a += hv[j] * w[j];
        acc[n] = a;
    }
    #pragma unroll
    for (int n = 0; n < Nt; ++n) {
        float v = acc[n];
        #pragma unroll
        for (int off = 32; off; off >>= 1) v += __shfl_down(v, off);
        if (lane == 0) emis[row * Nt + n] = v * mf + bout[n];
    }
}

// ---------- kernel 4: CRF LLH (one wave per batch) ----------
__global__ void crf_kernel(const int* __restrict__ tags, const int* __restrict__ mask,
                           const float* __restrict__ emis, const float* __restrict__ trans,
                           const float* __restrict__ startt, const float* __restrict__ endt,
                           float* __restrict__ out) {
    int b = blockIdx.x;
    int lane = threadIdx.x;

    float part = 0.f;
    int mc = 0;
    for (int t = lane; t < Tn; t += 64) {
        int mv = mask[t * Bn + b];
        mc += mv;
        if (t >= 1) {
            int tp = tags[(t - 1) * Bn + b], tc = tags[t * Bn + b];
            part += (trans[tp * Nt + tc] + emis[(t * Bn + b) * Nt + tc]) * (float)mv;
        }
    }
    #pragma unroll
    for (int off = 32; off; off >>= 1) {
        part += __shfl_down(part, off);
        mc += __shfl_down(mc, off);
    }
    float num = 0.f;
    if (lane == 0) {
        int t0g = tags[b];
        num = startt[t0g] + emis[b * Nt + t0g] + part;
        int last = mc - 1;
        num += endt[tags[last * Bn + b]];
    }

    if (lane < Nt) {
        int j = lane;
        float tr[6];
        #pragma unroll
        for (int i = 0; i < Nt; ++i) tr[i] = trans[i * Nt + j];
        float score = startt[j] + emis[b * Nt + j];
        float e_nx = emis[(Bn + b) * Nt + j];
        int   m_nx = mask[Bn + b];
        for (int t = 1; t < Tn; ++t) {
            float e = e_nx;
            int mv = m_nx;
            if (t + 1 < Tn) {
                e_nx = emis[((t + 1) * Bn + b) * Nt + j];
                m_nx = mask[(t + 1) * Bn + b];
            }
            float v[6];
            float mx = -1e30f;
            #pragma unroll
            for (int i = 0; i < Nt; ++i) { v[i] = __shfl(score, i) + tr[i]; mx = fmaxf(mx, v[i]); }
            float sm = 0.f;
            #pragma unroll
            for (int i = 0; i < Nt; ++i) sm += __expf(v[i] - mx);
            float nxtv = mx + __logf(sm) + e;
            score = mv > 0 ? nxtv : score;
        }
        float fvv = score + endt[j];
        float m2 = fvv;
        #pragma unroll
        for (int i = 0; i < Nt; ++i) m2 = fmaxf(m2, __shfl(fvv, i));
        float s2 = 0.f;
        #pragma unroll
        for (int i = 0; i < Nt; ++i) s2 += __expf(__shfl(fvv, i) - m2);
        if (lane == 0) {
            float denom = m2 + __logf(s2);
            atomicAdd(out, num - denom);
        }
    }
}

extern "C" void kernel_launch(void* const* d_in, const int* in_sizes, int n_in,
                              void* d_out, int out_size, void* d_ws, size_t ws_size,
                              hipStream_t stream) {
    (void)in_sizes; (void)n_in; (void)out_size; (void)ws_size;
    const int*   sent  = (const int*)d_in[0];
    const int*   tags  = (const int*)d_in[1];
    const int*   mask  = (const int*)d_in[2];
    const float* h0    = (const float*)d_in[3];
    const float* c0    = (const float*)d_in[4];
    const float* embed = (const float*)d_in[5];
    const float* Wihf  = (const float*)d_in[6];
    const float* Whhf  = (const float*)d_in[7];
    const float* bf_   = (const float*)d_in[8];
    const float* Wihb  = (const float*)d_in[9];
    const float* Whhb  = (const float*)d_in[10];
    const float* bb_   = (const float*)d_in[11];
    const float* Wout  = (const float*)d_in[12];
    const float* bout  = (const float*)d_in[13];
    const float* trans = (const float*)d_in[14];
    const float* stt   = (const float*)d_in[15];
    const float* ent   = (const float*)d_in[16];
    float* out = (float*)d_out;
    char* ws = (char*)d_ws;

    ushort_t* x_bf   = (ushort_t*)(ws + OFF_XBF);
    ushort_t* Wih_bf = (ushort_t*)(ws + OFF_WIH);
    ushort_t* Whh_bf = (ushort_t*)(ws + OFF_WHH);
    ushort_t* hbuf   = (ushort_t*)(ws + OFF_HBUF);
    float*    emis   = (float*)(ws + OFF_EMIS);

    // prep threads: 524288+262144+1048576+32768+1048576+1 = 2,916,353
    prep_kernel<<<11393, 256, 0, stream>>>(sent, embed, Wihf, Whhf, Wihb, Whhb,
                                           h0, out, x_bf, Wih_bf, Whh_bf, hbuf);
    lstm_kernel<<<128, 256, 0, stream>>>(x_bf, Wih_bf, Whh_bf, bf_, bb_, c0,
                                         mask, hbuf);
    emis_kernel<<<4096, 256, 0, stream>>>(hbuf, mask, Wout, bout, emis);
    crf_kernel<<<64, 64, 0, stream>>>(tags, mask, emis, trans, stt, ent, out);
}